// Round 1
// 429.045 us; speedup vs baseline: 1.0130x; 1.0130x over previous
//
#include <hip/hip_runtime.h>
#include <hip/hip_bf16.h>

// Problem constants (R=4096, S=128, V=3, F=35)
#define NPTS      524288            // R*S
#define OUT2_BASE 4718592           // NPTS*9  (rgb_in elements)

using bf16x8 = __attribute__((ext_vector_type(8))) short;   // MFMA A/B frag
using f32x4  = __attribute__((ext_vector_type(4))) float;   // MFMA C/D frag

// Weight workspace (ushort/bf16 in d_ws), [N][K] row-major, K padded, pads ZEROED:
//   WG [64][96]  @ 0      = bw1 mean part at cols 0..34, VAR part at cols 40..74
//                           (cols 35..39, 75..95 = 0) -- matches Xg LDS layout below
//   WF [64][72]  @ 6144   = bw1[:, 70:105](view part),  cols 35..71 = 0
//   W2 [32][72]  @ 10752  = bw2,  cols 64..71 = 0
//   V1 [32][40]  @ 13056  = vw1/3 (x/num_views folded), cols 32..39 = 0
//   V2 [32][40]  @ 14336  = vw2,  cols 32..39 = 0
//   R1 [32][104] @ 15616  = rw1,  cols 96..103 = 0
//   R2 [16][40]  @ 18944  = rw2,  cols 32..39 = 0

__device__ __forceinline__ ushort f2bf(float f) {
    union { float f; unsigned u; } v; v.f = f;
    unsigned u = v.u;
    unsigned r = u + 0x7fffu + ((u >> 16) & 1u);   // RTNE
    return (ushort)(r >> 16);
}
__device__ __forceinline__ uint pack2(float a, float b) {   // lo=bf16(a), hi=bf16(b)
    union { __hip_bfloat162 h; uint u; } cv;
    cv.h = __float22bfloat162_rn(make_float2(a, b));
    return cv.u;
}
__device__ __forceinline__ float eluf(float x) {
    return fmaxf(x, 0.f) + __expf(fminf(x, 0.f)) - 1.f;
}
__device__ __forceinline__ float sigm(float x) { return 1.f / (1.f + __expf(-x)); }

// unaligned-safe 8-float load (feat rows are 105 floats -> only 4B-aligned)
__device__ __forceinline__ void load8(const float* __restrict__ p, float* d) {
    __builtin_memcpy(d, p, 16);
    __builtin_memcpy(d + 4, p + 4, 16);
}

__global__ void prep_k(const float* __restrict__ bw1, const float* __restrict__ bw2,
                       const float* __restrict__ vw1, const float* __restrict__ vw2,
                       const float* __restrict__ rw1, const float* __restrict__ rw2,
                       ushort* __restrict__ w)
{
    int i = blockIdx.x * 256 + threadIdx.x;
    if (i < 6144) {                                   // WG [64][96] mean@0..34, var@40..74
        int n = i / 96, k = i % 96;
        float val = 0.f;
        if (k < 35)                 val = bw1[n * 105 + k];          // mean weights
        else if (k >= 40 && k < 75) val = bw1[n * 105 + 35 + (k - 40)]; // var weights
        w[i] = f2bf(val);
    } else if (i < 10752) {                           // WF [64][72]
        int t = i - 6144, n = t / 72, k = t % 72;
        w[i] = f2bf(k < 35 ? bw1[n * 105 + 70 + k] : 0.f);
    } else if (i < 13056) {                           // W2 [32][72]
        int t = i - 10752, n = t / 72, k = t % 72;
        w[i] = f2bf(k < 64 ? bw2[n * 64 + k] : 0.f);
    } else if (i < 14336) {                           // V1 [32][40] (/3 folded)
        int t = i - 13056, n = t / 40, k = t % 40;
        w[i] = f2bf(k < 32 ? vw1[n * 32 + k] * (1.f / 3.f) : 0.f);
    } else if (i < 15616) {                           // V2 [32][40]
        int t = i - 14336, n = t / 40, k = t % 40;
        w[i] = f2bf(k < 32 ? vw2[n * 32 + k] : 0.f);
    } else if (i < 18944) {                           // R1 [32][104]
        int t = i - 15616, n = t / 104, k = t % 104;
        w[i] = f2bf(k < 96 ? rw1[n * 96 + k] : 0.f);
    } else if (i < 19584) {                           // R2 [16][40]
        int t = i - 18944, n = t / 40, k = t % 40;
        w[i] = f2bf(k < 32 ? rw2[n * 32 + k] : 0.f);
    }
}

// 2 waves / block, 16 points / block. N-dim of every GEMM split across waves.
// LDS timeline-aliased into 3 regions (17.2 KB total -> ~9 blocks/CU):
//   shA 6912 B: h1[48][72] -> t1[48][72] -> r2b fp32[16][20]          (untouched in phase A)
//   shB 3328 B: Xg[16][96] (mean 0..34|grbg|var 40..74|grbg|0s 80..95) -> x2[16][104]
//   shC 6912 B: Xf[48][72] (data 0..34|grbg 35..39|0s 40..63) -> h2[48][72] -> r1[16][40]
// Barrier-minimal schedule: 7 __syncthreads (was 13). Every removed barrier was a
// WAR guard whose readers had already drained >=1 barrier earlier (per-buffer
// lifetime analysis in session notes). Phase A reads feat straight from global
// (L2/L3-hot) -- no fp32 staging, no whole-buffer zero-fill.
__global__ __launch_bounds__(128, 4) void mlp_k(
    const float* __restrict__ feat, const ushort* __restrict__ w,
    const float* __restrict__ bb1, const float* __restrict__ bb2,
    const float* __restrict__ vb1, const float* __restrict__ vb2,
    const float* __restrict__ rb1, const float* __restrict__ rb2,
    const float* __restrict__ rw3, const float* __restrict__ rb3,
    float* __restrict__ out)
{
    __shared__ __align__(16) ushort shA[3456];
    __shared__ __align__(16) ushort shB[1664];
    __shared__ __align__(16) ushort shC[3456];

    const int tid  = threadIdx.x;
    const int wv   = tid >> 6;          // wave id 0/1
    const int lane = tid & 63;
    const int n16  = lane & 15;
    const int quad = lane >> 4;
    const long long pbase = (long long)blockIdx.x * 16;

    const ushort* WG = w;
    const ushort* WF = w + 6144;
    const ushort* W2 = w + 10752;
    const ushort* V1 = w + 13056;
    const ushort* V2 = w + 14336;
    const ushort* R1 = w + 15616;
    const ushort* R2 = w + 18944;

    // per-lane biases for this wave's output columns
    float bb1v[2];
#pragma unroll
    for (int ntl = 0; ntl < 2; ++ntl) bb1v[ntl] = bb1[(wv * 2 + ntl) * 16 + n16];
    const float bb2v = bb2[wv * 16 + n16];
    const float vb1v = vb1[wv * 16 + n16];
    const float vb2v = vb2[wv * 16 + n16];
    const float rb1v = rb1[wv * 16 + n16];
    const float rb2v = rb2[n16];

    // ---- phase A: targeted pad zero-fill + build Xg/Xf from GLOBAL + rgb_in ----
    {
        const uint4 z = make_uint4(0u, 0u, 0u, 0u);
        // Xf pad cols 40..63 (rows 0..47): byte r*144+80, 48 B/row -> 3 uint4
        uint4* zc = (uint4*)shC;
        for (int i = tid; i < 144; i += 128) {
            int r = i / 3, c = i - r * 3;
            zc[r * 9 + 5 + c] = z;
        }
        // Xg pad cols 80..95 (rows 0..15): byte r*192+160, 32 B/row -> 2 uint4
        if (tid < 32) {
            uint4* zb = (uint4*)shB;
            int r = tid >> 1, c = tid & 1;
            zb[r * 12 + 10 + c] = z;
        }
        // rgb_in passthrough (fp32 exact), straight global->global (feat row is L2-hot)
        for (int i = tid; i < 144; i += 128) {
            int p = i / 9, r = i - p * 9, v = r / 3, c = r - v * 3;
            out[pbase * 9 + i] = feat[(pbase + p) * 105 + v * 35 + c];
        }
        // main build: 80 threads, one (point, 8-feature group) each
        if (tid < 80) {
            int p  = tid / 5;           // 0..15
            int g  = tid - p * 5;       // 0..4
            int k8 = g * 8;             // 0,8,16,24,32 (tail group has 3 valid feats)
            const float* row = feat + (pbase + p) * 105;
            float X0[8], X1[8], X2[8];
            load8(row + k8,      X0);   // view 0 (tail overreads into view1: finite, zero-weight)
            load8(row + 35 + k8, X1);   // view 1 (tail overreads into view2: same)
            if (k8 == 32 && (pbase + p) == (long long)NPTS - 1) {
                // very last point: row+70+32+7 would run off the array end
                X2[0] = row[102]; X2[1] = row[103]; X2[2] = row[104];
                X2[3] = 0.f; X2[4] = 0.f; X2[5] = 0.f; X2[6] = 0.f; X2[7] = 0.f;
            } else {
                load8(row + 70 + k8, X2);   // view 2
            }
            float M[8], VV[8];
#pragma unroll
            for (int j = 0; j < 8; ++j) {
                float a = X0[j], b = X1[j], c = X2[j];
                float m  = (a + b + c) * (1.f / 3.f);
                float da = a - m, db = b - m, dc = c - m;
                M[j]  = m;
                VV[j] = (da * da + db * db + dc * dc) * (1.f / 3.f);
            }
            // Xf: raw views, rows v*16+p, cols k8..k8+7 (one aligned uint4 each)
            *(uint4*)(shC + p * 72 + k8) =
                make_uint4(pack2(X0[0], X0[1]), pack2(X0[2], X0[3]),
                           pack2(X0[4], X0[5]), pack2(X0[6], X0[7]));
            *(uint4*)(shC + (16 + p) * 72 + k8) =
                make_uint4(pack2(X1[0], X1[1]), pack2(X1[2], X1[3]),
                           pack2(X1[4], X1[5]), pack2(X1[6], X1[7]));
            *(uint4*)(shC + (32 + p) * 72 + k8) =
                make_uint4(pack2(X2[0], X2[1]), pack2(X2[2], X2[3]),
                           pack2(X2[4], X2[5]), pack2(X2[6], X2[7]));
            // Xg: mean at col k8, var at col 40+k8 (16B-aligned; tail garbage hits zero weights)
            *(uint4*)(shB + p * 96 + k8) =
                make_uint4(pack2(M[0], M[1]), pack2(M[2], M[3]),
                           pack2(M[4], M[5]), pack2(M[6], M[7]));
            *(uint4*)(shB + p * 96 + 40 + k8) =
                make_uint4(pack2(VV[0], VV[1]), pack2(VV[2], VV[3]),
                           pack2(VV[4], VV[5]), pack2(VV[6], VV[7]));
        }
    }
    __syncthreads();                                  // BAR1: Xg/Xf ready

    const f32x4 Z = {0.f, 0.f, 0.f, 0.f};

    // ---- layer 1 (N split: this wave -> cols (wv*2+ntl)*16+n16) ----
    f32x4 Cg[2]    = {Z, Z};
    f32x4 Cf[3][2] = {{Z, Z}, {Z, Z}, {Z, Z}};
#pragma unroll
    for (int ks = 0; ks < 3; ++ks) {                 // K=96 : [mean|var]
        bf16x8 a = *(const bf16x8*)(shB + n16 * 96 + ks * 32 + quad * 8);
#pragma unroll
        for (int ntl = 0; ntl < 2; ++ntl) {
            bf16x8 b = *(const bf16x8*)(WG + ((wv * 2 + ntl) * 16 + n16) * 96 + ks * 32 + quad * 8);
            Cg[ntl] = __builtin_amdgcn_mfma_f32_16x16x32_bf16(a, b, Cg[ntl], 0, 0, 0);
        }
    }
#pragma unroll
    for (int ks = 0; ks < 2; ++ks) {                 // K=64 : view feat
        bf16x8 a0 = *(const bf16x8*)(shC + (0 * 16 + n16) * 72 + ks * 32 + quad * 8);
        bf16x8 a1 = *(const bf16x8*)(shC + (1 * 16 + n16) * 72 + ks * 32 + quad * 8);
        bf16x8 a2 = *(const bf16x8*)(shC + (2 * 16 + n16) * 72 + ks * 32 + quad * 8);
#pragma unroll
        for (int ntl = 0; ntl < 2; ++ntl) {
            bf16x8 b = *(const bf16x8*)(WF + ((wv * 2 + ntl) * 16 + n16) * 72 + ks * 32 + quad * 8);
            Cf[0][ntl] = __builtin_amdgcn_mfma_f32_16x16x32_bf16(a0, b, Cf[0][ntl], 0, 0, 0);
            Cf[1][ntl] = __builtin_amdgcn_mfma_f32_16x16x32_bf16(a1, b, Cf[1][ntl], 0, 0, 0);
            Cf[2][ntl] = __builtin_amdgcn_mfma_f32_16x16x32_bf16(a2, b, Cf[2][ntl], 0, 0, 0);
        }
    }
    // h1 = elu(Cf + Cg + bb1) -> shA [48][72] cols wv*32..wv*32+31
    // (shA untouched before this -- no barrier needed before these writes)
#pragma unroll
    for (int mt = 0; mt < 3; ++mt)
#pragma unroll
        for (int ntl = 0; ntl < 2; ++ntl) {
            float e0 = eluf(Cf[mt][ntl][0] + Cg[ntl][0] + bb1v[ntl]);
            float e1 = eluf(Cf[mt][ntl][1] + Cg[ntl][1] + bb1v[ntl]);
            float e2 = eluf(Cf[mt][ntl][2] + Cg[ntl][2] + bb1v[ntl]);
            float e3 = eluf(Cf[mt][ntl][3] + Cg[ntl][3] + bb1v[ntl]);
            int col = (wv * 2 + ntl) * 16 + n16;
            int r0  = (mt * 16 + quad * 4) * 72 + col;
            uint u01 = pack2(e0, e1), u23 = pack2(e2, e3);
            shA[r0]           = (ushort)u01;
            shA[r0 + 72]      = (ushort)(u01 >> 16);
            shA[r0 + 144]     = (ushort)u23;
            shA[r0 + 216]     = (ushort)(u23 >> 16);
        }
    __syncthreads();                                  // BAR2: h1 ready (Xf readers drained)

    // ---- layer 2 (N=32, wave owns cols wv*16+n16) ----
    f32x4 C2[3] = {Z, Z, Z};
#pragma unroll
    for (int ks = 0; ks < 2; ++ks) {
        bf16x8 a0 = *(const bf16x8*)(shA + (0 * 16 + n16) * 72 + ks * 32 + quad * 8);
        bf16x8 a1 = *(const bf16x8*)(shA + (1 * 16 + n16) * 72 + ks * 32 + quad * 8);
        bf16x8 a2 = *(const bf16x8*)(shA + (2 * 16 + n16) * 72 + ks * 32 + quad * 8);
        bf16x8 b  = *(const bf16x8*)(W2 + (wv * 16 + n16) * 72 + ks * 32 + quad * 8);
        C2[0] = __builtin_amdgcn_mfma_f32_16x16x32_bf16(a0, b, C2[0], 0, 0, 0);
        C2[1] = __builtin_amdgcn_mfma_f32_16x16x32_bf16(a1, b, C2[1], 0, 0, 0);
        C2[2] = __builtin_amdgcn_mfma_f32_16x16x32_bf16(a2, b, C2[2], 0, 0, 0);
    }
    // h2 stores go straight to shC: its last readers (layer-1 Xf MFMAs) drained at BAR2
    float h2r[3][4];
#pragma unroll
    for (int mt = 0; mt < 3; ++mt) {
        float e0 = eluf(C2[mt][0] + bb2v);
        float e1 = eluf(C2[mt][1] + bb2v);
        float e2 = eluf(C2[mt][2] + bb2v);
        float e3 = eluf(C2[mt][3] + bb2v);
        h2r[mt][0] = e0; h2r[mt][1] = e1; h2r[mt][2] = e2; h2r[mt][3] = e3;
        int r0 = (mt * 16 + quad * 4) * 72 + wv * 16 + n16;
        uint u01 = pack2(e0, e1), u23 = pack2(e2, e3);
        shC[r0]       = (ushort)u01;
        shC[r0 + 72]  = (ushort)(u01 >> 16);
        shC[r0 + 144] = (ushort)u23;
        shC[r0 + 216] = (ushort)(u23 >> 16);
    }
    __syncthreads();                                  // BAR3: h2 ready (h1 readers drained)

    // ---- vis layer 1 (K=32, cols 0..31 of shC only) ----
    f32x4 T1[3] = {Z, Z, Z};
    {
        bf16x8 a0 = *(const bf16x8*)(shC + (0 * 16 + n16) * 72 + quad * 8);
        bf16x8 a1 = *(const bf16x8*)(shC + (1 * 16 + n16) * 72 + quad * 8);
        bf16x8 a2 = *(const bf16x8*)(shC + (2 * 16 + n16) * 72 + quad * 8);
        bf16x8 b  = *(const bf16x8*)(V1 + (wv * 16 + n16) * 40 + quad * 8);
        T1[0] = __builtin_amdgcn_mfma_f32_16x16x32_bf16(a0, b, T1[0], 0, 0, 0);
        T1[1] = __builtin_amdgcn_mfma_f32_16x16x32_bf16(a1, b, T1[1], 0, 0, 0);
        T1[2] = __builtin_amdgcn_mfma_f32_16x16x32_bf16(a2, b, T1[2], 0, 0, 0);
    }
    // t1 -> shA cols 0..31: h1 readers drained at BAR3 -- no extra barrier
#pragma unroll
    for (int mt = 0; mt < 3; ++mt) {
        float e0 = eluf(T1[mt][0] + vb1v);
        float e1 = eluf(T1[mt][1] + vb1v);
        float e2 = eluf(T1[mt][2] + vb1v);
        float e3 = eluf(T1[mt][3] + vb1v);
        int r0 = (mt * 16 + quad * 4) * 72 + wv * 16 + n16;
        uint u01 = pack2(e0, e1), u23 = pack2(e2, e3);
        shA[r0]       = (ushort)u01;
        shA[r0 + 72]  = (ushort)(u01 >> 16);
        shA[r0 + 144] = (ushort)u23;
        shA[r0 + 216] = (ushort)(u23 >> 16);
    }
    __syncthreads();                                  // BAR4: t1 ready

    // ---- vis layer 2 + residual -> x2 (shB [16][104]) ----
    f32x4 T2[3] = {Z, Z, Z};
    {
        bf16x8 a0 = *(const bf16x8*)(shA + (0 * 16 + n16) * 72 + quad * 8);
        bf16x8 a1 = *(const bf16x8*)(shA + (1 * 16 + n16) * 72 + quad * 8);
        bf16x8 a2 = *(const bf16x8*)(shA + (2 * 16 + n16) * 72 + quad * 8);
        bf16x8 b  = *(const bf16x8*)(V2 + (wv * 16 + n16) * 40 + quad * 8);
        T2[0] = __builtin_amdgcn_mfma_f32_16x16x32_bf16(a0, b, T2[0], 0, 0, 0);
        T2[1] = __builtin_amdgcn_mfma_f32_16x16x32_bf16(a1, b, T2[1], 0, 0, 0);
        T2[2] = __builtin_amdgcn_mfma_f32_16x16x32_bf16(a2, b, T2[2], 0, 0, 0);
    }
    // x2 -> shB: its last readers (layer-1 Xg MFMAs) drained at BAR2 -- no extra barrier
#pragma unroll
    for (int mt = 0; mt < 3; ++mt) {
        float x0  = h2r[mt][0] + eluf(T2[mt][0] + vb2v);
        float x1  = h2r[mt][1] + eluf(T2[mt][1] + vb2v);
        float x2v = h2r[mt][2] + eluf(T2[mt][2] + vb2v);
        float x3  = h2r[mt][3] + eluf(T2[mt][3] + vb2v);
        int col = mt * 32 + wv * 16 + n16;            // v*32 + c concat layout
        int r0  = (quad * 4) * 104 + col;
        uint u01 = pack2(x0, x1), u23 = pack2(x2v, x3);
        shB[r0]       = (ushort)u01;
        shB[r0 + 104] = (ushort)(u01 >> 16);
        shB[r0 + 208] = (ushort)u23;
        shB[r0 + 312] = (ushort)(u23 >> 16);
    }
    __syncthreads();                                  // BAR5: x2 ready

    // ---- r1 = elu(x2 @ R1^T + rb1), N=32 split ----
    f32x4 CR = Z;
#pragma unroll
    for (int ks = 0; ks < 3; ++ks) {                  // K=96
        bf16x8 a = *(const bf16x8*)(shB + n16 * 104 + ks * 32 + quad * 8);
        bf16x8 b = *(const bf16x8*)(R1 + (wv * 16 + n16) * 104 + ks * 32 + quad * 8);
        CR = __builtin_amdgcn_mfma_f32_16x16x32_bf16(a, b, CR, 0, 0, 0);
    }
    // r1 -> shC [16][40]: shC's last readers (vis-1 h2 MFMAs) drained at BAR4
    {
        float e0 = eluf(CR[0] + rb1v);
        float e1 = eluf(CR[1] + rb1v);
        float e2 = eluf(CR[2] + rb1v);
        float e3 = eluf(CR[3] + rb1v);
        int r0 = (quad * 4) * 40 + wv * 16 + n16;
        uint u01 = pack2(e0, e1), u23 = pack2(e2, e3);
        shC[r0]       = (ushort)u01;
        shC[r0 + 40]  = (ushort)(u01 >> 16);
        shC[r0 + 80]  = (ushort)u23;
        shC[r0 + 120] = (ushort)(u23 >> 16);
    }
    __syncthreads();                                  // BAR6: r1 ready

    // ---- r2 = elu(r1 @ R2^T + rb2) -> fp32 shA [16][20] ----
    f32x4 C3 = Z;
    {
        bf16x8 a = *(const bf16x8*)(shC + n16 * 40 + quad * 8);
        bf16x8 b = *(const bf16x8*)(R2 + n16 * 40 + quad * 8);
        C3 = __builtin_amdgcn_mfma_f32_16x16x32_bf16(a, b, C3, 0, 0, 0);
    }
    // r2 -> shA fp32: shA's last readers (vis-2 t1 MFMAs) drained at BAR5
    {
        float* r2b = (float*)shA;
#pragma unroll
        for (int rr = 0; rr < 2; ++rr) {              // wave wv writes r = 2wv+rr
            int r = 2 * wv + rr;
            r2b[(quad * 4 + r) * 20 + n16] = eluf(C3[r] + rb2v);
        }
    }
    __syncthreads();                                  // BAR7: r2 ready

    // ---- final 16 -> 3 + sigmoid (fp32), vectorized LDS reads, coalesced store ----
    if (tid < 48) {
        const float* r2b = (const float*)shA;
        int p = tid / 3, c = tid - p * 3;
        const float4* rr = (const float4*)(r2b + p * 20);
        const float4* w3 = (const float4*)(rw3 + c * 16);
        float4 a0 = rr[0], a1 = rr[1], a2 = rr[2], a3 = rr[3];
        float4 q0 = w3[0], q1 = w3[1], q2 = w3[2], q3 = w3[3];
        float s = rb3[c];
        s += a0.x * q0.x + a0.y * q0.y + a0.z * q0.z + a0.w * q0.w;
        s += a1.x * q1.x + a1.y * q1.y + a1.z * q1.z + a1.w * q1.w;
        s += a2.x * q2.x + a2.y * q2.y + a2.z * q2.z + a2.w * q2.w;
        s += a3.x * q3.x + a3.y * q3.y + a3.z * q3.z + a3.w * q3.w;
        out[OUT2_BASE + pbase * 3 + tid] = sigm(s);
    }
}

extern "C" void kernel_launch(void* const* d_in, const int* in_sizes, int n_in,
                              void* d_out, int out_size, void* d_ws, size_t ws_size,
                              hipStream_t stream) {
    const float* feat = (const float*)d_in[0];
    const float* bw1  = (const float*)d_in[1];
    const float* bb1  = (const float*)d_in[2];
    const float* bw2  = (const float*)d_in[3];
    const float* bb2  = (const float*)d_in[4];
    const float* vw1  = (const float*)d_in[5];
    const float* vb1  = (const float*)d_in[6];
    const float* vw2  = (const float*)d_in[7];
    const float* vb2  = (const float*)d_in[8];
    const float* rw1  = (const float*)d_in[9];
    const float* rb1  = (const float*)d_in[10];
    const float* rw2  = (const float*)d_in[11];
    const float* rb2  = (const float*)d_in[12];
    const float* rw3  = (const float*)d_in[13];
    const float* rb3  = (const float*)d_in[14];
    ushort* w  = (ushort*)d_ws;
    float* out = (float*)d_out;

    hipLaunchKernelGGL(prep_k, dim3(77), dim3(256), 0, stream,
                       bw1, bw2, vw1, vw2, rw1, rw2, w);
    hipLaunchKernelGGL(mlp_k, dim3(NPTS / 16), dim3(128), 0, stream,
                       feat, w, bb1, bb2, vb1, vb2, rb1, rb2, rw3, rb3, out);
}